// Round 2
// baseline (446.009 us; speedup 1.0000x reference)
//
#include <hip/hip_runtime.h>
#include <hip/hip_bf16.h>
#include <math.h>

typedef __bf16 bf16;
typedef __bf16 bf16x8 __attribute__((ext_vector_type(8)));
typedef float f32x4 __attribute__((ext_vector_type(4)));

#define C_DIM 512
#define S_DIM 8192

__device__ __forceinline__ void async_ld16(const void* g, void* l) {
    __builtin_amdgcn_global_load_lds(
        (const __attribute__((address_space(1))) unsigned int*)g,
        (__attribute__((address_space(3))) unsigned int*)l, 16, 0, 0);
}

// f32 -> OCP e4m3 via HW cvt (gfx950: v_cvt_pk_fp8_f32 emits OCP format)
__device__ __forceinline__ unsigned char to_fp8(float v) {
    return (unsigned char)(__builtin_amdgcn_cvt_pk_fp8_f32(v, v, 0, false) & 0xFF);
}

// ---------------- Kernel 0: dtype detect (wave ballot) + aux zeroing -----
__global__ void detect_kernel(const unsigned short* __restrict__ xu, int* __restrict__ flag) {
    int j = threadIdx.x;   // 64 threads
    for (int i = 16 + j; i < 320; i += 64) flag[i] = 0;   // zero counter + cnt[256]
    unsigned e = (xu[2 * j] >> 7) & 0xFF;
    unsigned long long m = __ballot(e >= 90 && e <= 140);
    if (j == 0) *flag = (__popcll(m) >= 48) ? 1 : 0;   // 1 = bf16, 0 = fp32
}

// ---------------- Kernel 0b: all 4 weights -> bf16 (one launch) ----------
__global__ __launch_bounds__(256) void convert_kernel(const void* __restrict__ s0,
                                                      const void* __restrict__ s1,
                                                      const void* __restrict__ s2,
                                                      const void* __restrict__ s3,
                                                      bf16* __restrict__ dst,
                                                      const int* __restrict__ flag) {
    int y = blockIdx.y;
    const void* srcs[4] = {s0, s1, s2, s3};
    const void* src = srcs[y];
    int i = blockIdx.x * 256 + threadIdx.x;
    bf16* d = dst + (size_t)y * 262144;
    if (*flag) {
        volatile const bf16* s = (volatile const bf16*)src;
        d[i] = s[i];
    } else {
        volatile const float* s = (volatile const float*)src;
        d[i] = (bf16)s[i];
    }
}

// ---------------- Kernel 1: per-token inverse RMS norm (coalesced) -------
__global__ __launch_bounds__(256) void rms_kernel(const void* __restrict__ x,
                                                  float* __restrict__ r,
                                                  const int* __restrict__ flag) {
    __shared__ float red[4][64];
    int b  = blockIdx.x >> 7;
    int s0 = (blockIdx.x & 127) * 64;
    int sl = threadIdx.x & 63;
    int cq = threadIdx.x >> 6;   // 0..3 -> 128-channel slab
    float acc = 0.f;
    if (*flag) {
        const bf16* xp = (const bf16*)x + ((size_t)b * C_DIM + cq * 128) * S_DIM + s0 + sl;
        for (int c = 0; c < 128; ++c) { float v = (float)xp[(size_t)c * S_DIM]; acc += v * v; }
    } else {
        const float* xp = (const float*)x + ((size_t)b * C_DIM + cq * 128) * S_DIM + s0 + sl;
        for (int c = 0; c < 128; ++c) { float v = xp[(size_t)c * S_DIM]; acc += v * v; }
    }
    red[cq][sl] = acc;
    __syncthreads();
    if (cq == 0) {
        float t = red[0][sl] + red[1][sl] + red[2][sl] + red[3][sl];
        r[b * S_DIM + s0 + sl] = 22.627416997969522f / fmaxf(sqrtf(t), 1e-12f);
    }
}

// ------------- Kernel 2: transpose+scale -> hn[b][s][c] (token-major) ----
__global__ __launch_bounds__(256) void hn_kernel(const void* __restrict__ x,
                                                 const void* __restrict__ gamma,
                                                 const float* __restrict__ r,
                                                 bf16* __restrict__ hn,
                                                 const int* __restrict__ flag) {
    __shared__ float tile[64][65];
    int f  = *flag;
    int b  = blockIdx.z;
    int c0 = blockIdx.y * 64;
    int s0 = blockIdx.x * 64;
    int col = threadIdx.x & 63;
    int row = threadIdx.x >> 6;
    if (f) {
        const bf16* xp = (const bf16*)x + ((size_t)b * C_DIM + c0) * S_DIM + s0;
        for (int i = 0; i < 16; ++i)
            tile[row + i * 4][col] = (float)xp[(size_t)(row + i * 4) * S_DIM + col];
    } else {
        const float* xp = (const float*)x + ((size_t)b * C_DIM + c0) * S_DIM + s0;
        for (int i = 0; i < 16; ++i)
            tile[row + i * 4][col] = xp[(size_t)(row + i * 4) * S_DIM + col];
    }
    __syncthreads();
    float g;
    if (f) g = (float)((const bf16*)gamma)[c0 + col];
    else   g = ((const float*)gamma)[c0 + col];
    bf16* hp = hn + ((size_t)b * S_DIM + s0) * C_DIM + c0;
    for (int i = 0; i < 16; ++i) {
        int s_l = row + i * 4;
        float rv = r[b * S_DIM + s0 + s_l];
        hp[(size_t)s_l * C_DIM + col] = (bf16)(tile[col][s_l] * rv * g);
    }
}

// ------------- Kernel 3: GEMM  out[m][n] = A[m][:] . W[n][:] + bias -------
// mode 0: out fp8 token-major [m][n]                          (q)
// mode 3: out fp8 K-frag tiled [b][s/32][kcg64][key32][kch8]  (k)
// mode 1: out fp8 V-frag tiled [b][s/32][kq4][ch512][k8]      (v)
// mode 2: out (dtype per flag) [b][c][s] + residual           (final)
__global__ __launch_bounds__(256, 2) void gemm_kernel(const bf16* __restrict__ A,
                                                      const bf16* __restrict__ W,
                                                      const void* __restrict__ bias,
                                                      const void* __restrict__ resid,
                                                      void* __restrict__ out,
                                                      int mode,
                                                      const int* __restrict__ flag) {
    __shared__ bf16 As[128 * 40];
    __shared__ bf16 Bs[128 * 40];
    int f  = *flag;
    int m0 = blockIdx.x * 128;
    int n0 = blockIdx.y * 128;
    int tid  = threadIdx.x;
    int lane = tid & 63;
    int wave = tid >> 6;
    int wm = (wave & 1) * 64;
    int wn = (wave >> 1) * 64;
    int l15  = lane & 15;
    int quad = lane >> 4;

    f32x4 acc[4][4] = {};
    for (int k0 = 0; k0 < C_DIM; k0 += 32) {
        __syncthreads();
        for (int u = tid; u < 512; u += 256) {
            int rrow = u >> 2;
            int cc = (u & 3) * 8;
            *(bf16x8*)&As[rrow * 40 + cc] =
                *(const bf16x8*)&A[(size_t)(m0 + rrow) * C_DIM + k0 + cc];
            *(bf16x8*)&Bs[rrow * 40 + cc] =
                *(const bf16x8*)&W[(size_t)(n0 + rrow) * C_DIM + k0 + cc];
        }
        __syncthreads();
        bf16x8 af[4], bfr[4];
#pragma unroll
        for (int i = 0; i < 4; ++i)
            af[i] = *(bf16x8*)&As[(wm + i * 16 + l15) * 40 + quad * 8];
#pragma unroll
        for (int j = 0; j < 4; ++j)
            bfr[j] = *(bf16x8*)&Bs[(wn + j * 16 + l15) * 40 + quad * 8];
#pragma unroll
        for (int i = 0; i < 4; ++i)
#pragma unroll
            for (int j = 0; j < 4; ++j)
                acc[i][j] = __builtin_amdgcn_mfma_f32_16x16x32_bf16(af[i], bfr[j], acc[i][j], 0, 0, 0);
    }
    if (mode == 0) {
        unsigned char* op = (unsigned char*)out;
#pragma unroll
        for (int i = 0; i < 4; ++i)
#pragma unroll
            for (int j = 0; j < 4; ++j)
#pragma unroll
                for (int rg = 0; rg < 4; ++rg) {
                    int m = m0 + wm + i * 16 + quad * 4 + rg;
                    int n = n0 + wn + j * 16 + l15;
                    float bv = f ? (float)((const bf16*)bias)[n] : ((const float*)bias)[n];
                    op[(size_t)m * C_DIM + n] = to_fp8(acc[i][j][rg] + bv);
                }
    } else if (mode == 3) {
        unsigned char* op = (unsigned char*)out;
#pragma unroll
        for (int i = 0; i < 4; ++i)
#pragma unroll
            for (int j = 0; j < 4; ++j)
#pragma unroll
                for (int rg = 0; rg < 4; ++rg) {
                    int m = m0 + wm + i * 16 + quad * 4 + rg;   // key token
                    int n = n0 + wn + j * 16 + l15;             // k-channel
                    float bv = f ? (float)((const bf16*)bias)[n] : ((const float*)bias)[n];
                    size_t idx = ((((size_t)(m >> 5) * 64 + (n >> 3)) * 32 + (m & 31)) * 8) + (n & 7);
                    op[idx] = to_fp8(acc[i][j][rg] + bv);
                }
    } else if (mode == 1) {
        unsigned char* op = (unsigned char*)out;
#pragma unroll
        for (int i = 0; i < 4; ++i)
#pragma unroll
            for (int j = 0; j < 4; ++j)
#pragma unroll
                for (int rg = 0; rg < 4; ++rg) {
                    int m = m0 + wm + i * 16 + quad * 4 + rg;   // key token
                    int n = n0 + wn + j * 16 + l15;             // channel
                    float bv = f ? (float)((const bf16*)bias)[n] : ((const float*)bias)[n];
                    size_t idx = ((((size_t)(m >> 5) * 4 + ((m >> 3) & 3)) * 512 + n) * 8) + (m & 7);
                    op[idx] = to_fp8(acc[i][j][rg] + bv);
                }
    } else if (f) {
        bf16* op = (bf16*)out;
        const bf16* rp = (const bf16*)resid;
#pragma unroll
        for (int i = 0; i < 4; ++i)
#pragma unroll
            for (int j = 0; j < 4; ++j)
#pragma unroll
                for (int rg = 0; rg < 4; ++rg) {
                    int m = m0 + wm + i * 16 + quad * 4 + rg;
                    int n = n0 + wn + j * 16 + l15;
                    float bv = (float)((const bf16*)bias)[n];
                    int b = m >> 13, s = m & 8191;
                    size_t idx = ((size_t)b * C_DIM + n) * S_DIM + s;
                    op[idx] = (bf16)(acc[i][j][rg] + bv + (float)rp[idx]);
                }
    } else {
        float* op = (float*)out;
        const float* rp = (const float*)resid;
#pragma unroll
        for (int i = 0; i < 4; ++i)
#pragma unroll
            for (int j = 0; j < 4; ++j)
#pragma unroll
                for (int rg = 0; rg < 4; ++rg) {
                    int m = m0 + wm + i * 16 + quad * 4 + rg;
                    int n = n0 + wn + j * 16 + l15;
                    float bv = ((const float*)bias)[n];
                    int b = m >> 13, s = m & 8191;
                    size_t idx = ((size_t)b * C_DIM + n) * S_DIM + s;
                    op[idx] = acc[i][j][rg] + bv + rp[idx];
                }
    }
}

// ------------- Kernel 4a: paired-tile pipelined split flash attention ----
// 256 blocks x 512 threads (8 waves, 1 block/CU, ~103 KB LDS -> 8 waves/CU).
// Two q-tiles of the SAME frame (p, p+8) share one K/V stream: waves 0-3 own
// tile A, waves 4-7 own tile B -> K/V staged ONCE per 2 tiles of work
// (halves HBM fetch + staging). K/V TRIPLE-buffered; raw s_barrier with
// counted s_waitcnt vmcnt(4) so each prefetch gets ~2 iterations to land
// (no vmcnt(0) drain in the steady-state loop). QK accumulation split into
// 4 independent chains (depth 8) for MFMA latency hiding.
// Iteration space: 18432 = 2 batches x sum_f 8 pairs x 32(f+1) chunks;
// block's contiguous 72-iter span crosses pair boundaries -> flush both
// tiles' normalized partials to atomically-allocated slots (<=766 total).
__global__ __launch_bounds__(512, 2) void attn_split_kernel(const unsigned char* __restrict__ q,
                                                            const unsigned char* __restrict__ k,
                                                            const unsigned char* __restrict__ vt,
                                                            bf16* __restrict__ part,
                                                            float* __restrict__ lsum,
                                                            int* __restrict__ counter,
                                                            int* __restrict__ cnt,
                                                            int* __restrict__ slist) {
    __shared__ unsigned char Ks[3][16384];   // 48 KB
    __shared__ unsigned char Vs[3][16384];   // 48 KB
    __shared__ unsigned char Ps[8][16 * 40]; // 5 KB
    __shared__ int slot_sh;
    int tid  = threadIdx.x;
    int lane = tid & 63;
    int wave = tid >> 6;
    int qgrp = wave >> 2;     // 0 = tile p, 1 = tile p+8
    int w4   = wave & 3;      // 16-row slab within tile
    int l15  = lane & 15;
    int quad = lane >> 4;

    // ---- decode start state for g0 = 72*blockIdx ----
    // per batch: frame f spans [128f(f+1), 128(f+1)(f+2)) iters; pair len L=32(f+1)
    int g0 = blockIdx.x * 72;
    int b0 = (g0 >= 9216) ? 1 : 0;
    int r  = g0 - b0 * 9216;
    int f0 = 0;
    while (r >= 128 * (f0 + 1) * (f0 + 2)) ++f0;
    int L0  = 32 * (f0 + 1);
    int rr  = r - 128 * f0 * (f0 + 1);
    int p0  = rr / L0;
    int c0  = rr - p0 * L0;          // key-chunk index (absolute, frame range starts at 0)

    // state advance helper (uniform scalar)
    auto adv = [](int& b, int& f, int& p, int& c, int& L) {
        if (++c == L) {
            c = 0;
            if (++p == 8) {
                p = 0;
                if (++f == 8) { f = 0; L = 32; ++b; }
                else L += 32;
            }
        }
    };
    int b1 = b0, f1 = f0, p1 = p0, c1 = c0, L1 = L0; adv(b1, f1, p1, c1, L1);
    int b2 = b1, f2 = f1, p2 = p1, c2 = c1, L2 = L1; adv(b2, f2, p2, c2, L2);

    // ---- Q fragments for current tile ----
    long qf[16];
    {
        int qbase = (f0 * 16 + p0 + qgrp * 8) * 64 + w4 * 16;
        const unsigned char* qp = q + (size_t)(b0 * S_DIM + qbase + l15) * C_DIM;
#pragma unroll
        for (int ks = 0; ks < 16; ++ks)
            qf[ks] = *(const long*)&qp[ks * 32 + quad * 8];
    }

    f32x4 oacc[32] = {};
    float l_i[4] = {0.f, 0.f, 0.f, 0.f};
    const float scale = 0.044194173824159216f;  // 1/sqrt(512)

    // stage one 32-key chunk (16 KB K + 16 KB V) with 512 threads: 4 loads/thread
    auto stage = [&](int buf, int sb, int sc) {
        const unsigned char* kc = k  + ((size_t)(sb * 256 + sc) << 14);
        const unsigned char* vc = vt + ((size_t)(sb * 256 + sc) << 14);
#pragma unroll
        for (int j = 0; j < 2; ++j) {
            int off = wave * 2048 + j * 1024;
            async_ld16(kc + off + lane * 16, &Ks[buf][off]);
            async_ld16(vc + off + lane * 16, &Vs[buf][off]);
        }
    };

    // flush both tiles' partials for tile-triple (fb,ff,fp)
    auto do_flush = [&](int fb, int ff, int fp) {
        int ordA = fb * 128 + ff * 16 + fp;
        if (tid == 0) {
            int s = atomicAdd(counter, 2);
            int posA = atomicAdd(&cnt[ordA], 1);
            slist[ordA * 8 + posA] = s;
            int posB = atomicAdd(&cnt[ordA + 8], 1);
            slist[(ordA + 8) * 8 + posB] = s + 1;
            slot_sh = s;
        }
        __syncthreads();
        int slot = slot_sh + qgrp;
        float ls[4];
#pragma unroll
        for (int rg = 0; rg < 4; ++rg) {
            float v = l_i[rg];
            for (int d = 1; d < 16; d <<= 1) v += __shfl_xor(v, d);
            ls[rg] = v;
        }
        float rinv[4];
#pragma unroll
        for (int rg = 0; rg < 4; ++rg) rinv[rg] = 1.f / ls[rg];
        bf16* ppd = part + ((size_t)slot * 64 + w4 * 16) * C_DIM;
#pragma unroll
        for (int dn = 0; dn < 32; ++dn)
#pragma unroll
            for (int rg = 0; rg < 4; ++rg)
                ppd[(size_t)(quad * 4 + rg) * C_DIM + dn * 16 + l15] =
                    (bf16)(oacc[dn][rg] * rinv[rg]);
        if (l15 == 0) {
#pragma unroll
            for (int rg = 0; rg < 4; ++rg)
                lsum[slot * 64 + w4 * 16 + quad * 4 + rg] = ls[rg];
        }
    };

    // prologue: chunk g0 -> buf0, g0+1 -> buf1; wait first 4 loads only
    stage(0, b0, c0);
    stage(1, b1, c1);
    __builtin_amdgcn_sched_barrier(0);
    asm volatile("s_waitcnt vmcnt(4)" ::: "memory");
    __builtin_amdgcn_s_barrier();
    __builtin_amdgcn_sched_barrier(0);

    int pb = b0, pfr = f0, ppr = p0;
    for (int i = 0; i < 72; ++i) {
        // ---- flush at tile boundary (uniform condition; rare) ----
        if (i > 0 && (p0 != ppr || f0 != pfr || b0 != pb)) {
            do_flush(pb, pfr, ppr);
#pragma unroll
            for (int dn = 0; dn < 32; ++dn) oacc[dn] = (f32x4){0.f, 0.f, 0.f, 0.f};
#pragma unroll
            for (int rg = 0; rg < 4; ++rg) l_i[rg] = 0.f;
            int qbase = (f0 * 16 + p0 + qgrp * 8) * 64 + w4 * 16;
            const unsigned char* qp = q + (size_t)(b0 * S_DIM + qbase + l15) * C_DIM;
#pragma unroll
            for (int ks = 0; ks < 16; ++ks)
                qf[ks] = *(const long*)&qp[ks * 32 + quad * 8];
        }
        pb = b0; pfr = f0; ppr = p0;

        // ---- prefetch chunk g0+i+2 into ring buffer ----
        int bc = i % 3;
        int bp = bc + 2; if (bp >= 3) bp -= 3;
        stage(bp, b2, c2);

        const unsigned char* kb = Ks[bc];
        const unsigned char* vb = Vs[bc];
        // S = q . k^T : 4 independent chains (2 key-subtiles x 2 K-halves)
        f32x4 stA[2] = {}, stB[2] = {};
#pragma unroll
        for (int nt = 0; nt < 2; ++nt) {
#pragma unroll
            for (int ks = 0; ks < 8; ++ks) {
                long kfa = *(const long*)&kb[(ks * 4 + quad) * 256 + (nt * 16 + l15) * 8];
                stA[nt] = __builtin_amdgcn_mfma_f32_16x16x32_fp8_fp8(qf[ks], kfa, stA[nt], 0, 0, 0);
                long kfb = *(const long*)&kb[((ks + 8) * 4 + quad) * 256 + (nt * 16 + l15) * 8];
                stB[nt] = __builtin_amdgcn_mfma_f32_16x16x32_fp8_fp8(qf[ks + 8], kfb, stB[nt], 0, 0, 0);
            }
        }
        // softmax-lite: raw exp (scores bounded), per-lane l accumulation
        float p0v[4], p1v[4];
#pragma unroll
        for (int rg = 0; rg < 4; ++rg) {
            p0v[rg] = __expf((stA[0][rg] + stB[0][rg]) * scale);
            p1v[rg] = __expf((stA[1][rg] + stB[1][rg]) * scale);
            l_i[rg] += p0v[rg] + p1v[rg];
        }
        // P (C layout) -> per-wave fp8 LDS scratch -> A layout (same-wave)
        unsigned char* pw = Ps[wave];
#pragma unroll
        for (int rg = 0; rg < 4; ++rg) {
            pw[(quad * 4 + rg) * 40 + l15] = to_fp8(p0v[rg]);
            pw[(quad * 4 + rg) * 40 + 16 + l15] = to_fp8(p1v[rg]);
        }
        long pf = *(const long*)&pw[l15 * 40 + quad * 8];
        // PV: vf 8 B at quad*4096 + ch*8 (independent chains)
#pragma unroll
        for (int dn = 0; dn < 32; ++dn) {
            long vf = *(const long*)&vb[quad * 4096 + (dn * 16 + l15) * 8];
            oacc[dn] = __builtin_amdgcn_mfma_f32_16x16x32_fp8_fp8(pf, vf, oacc[dn], 0, 0, 0);
        }

        // ---- advance states ----
        b0 = b1; f0 = f1; p0 = p1; c0 = c1; L0 = L1;
        b1 = b2; f1 = f2; p1 = p2; c1 = c2; L1 = L2;
        if (g0 + i + 3 < 18432) adv(b2, f2, p2, c2, L2);

        // ---- end-of-iteration: counted-vmcnt barrier (no full drain) ----
        // oldest 4 outstanding loads (chunk i+1) must land; chunk i+2 stays in flight
        __builtin_amdgcn_sched_barrier(0);
        asm volatile("s_waitcnt vmcnt(4)" ::: "memory");
        __builtin_amdgcn_s_barrier();
        __builtin_amdgcn_sched_barrier(0);
    }
    do_flush(pb, pfr, ppr);
}

// ------------- Kernel 4b: non-split fallback flash attention -------------
__global__ __launch_bounds__(256, 2) void attn_kernel(const unsigned char* __restrict__ q,
                                                      const unsigned char* __restrict__ k,
                                                      const unsigned char* __restrict__ vt,
                                                      bf16* __restrict__ ob) {
    __shared__ unsigned char Ks[2][16384];
    __shared__ unsigned char Vs[2][16384];
    __shared__ unsigned char Ps[4][16 * 40];
    int id = blockIdx.x;
    int b = id >> 7;
    int t = id & 127;
    int q0 = t * 64;
    int kc1 = ((t >> 4) + 1) << 10;
    int tid  = threadIdx.x;
    int lane = tid & 63;
    int wave = tid >> 6;
    int l15  = lane & 15;
    int quad = lane >> 4;
    int qbase = q0 + wave * 16;
    int nchunks = kc1 >> 5;

    long qf[16];
    const unsigned char* qp = q + (size_t)(b * S_DIM + qbase + l15) * C_DIM;
#pragma unroll
    for (int ks = 0; ks < 16; ++ks)
        qf[ks] = *(const long*)&qp[ks * 32 + quad * 8];

    f32x4 oacc[32] = {};
    float l_i[4] = {0.f, 0.f, 0.f, 0.f};
    const float scale = 0.044194173824159216f;

    const unsigned char* kbase = k  + ((size_t)(b * 256) << 14);
    const unsigned char* vbase = vt + ((size_t)(b * 256) << 14);

#pragma unroll
    for (int j = 0; j < 4; ++j) {
        int base = (j * 4 + wave) * 1024;
        async_ld16(kbase + base + lane * 16, &Ks[0][base]);
        async_ld16(vbase + base + lane * 16, &Vs[0][base]);
    }
    __syncthreads();

    for (int p = 0; p < nchunks; ++p) {
        int pn = (p + 1 < nchunks) ? (p + 1) : p;
        const unsigned char* ksub = kbase + ((size_t)pn << 14);
        const unsigned char* vsub = vbase + ((size_t)pn << 14);
        unsigned char* kd = Ks[(p + 1) & 1];
        unsigned char* vd = Vs[(p + 1) & 1];
#pragma unroll
        for (int j = 0; j < 4; ++j) {
            int base = (j * 4 + wave) * 1024;
            async_ld16(ksub + base + lane * 16, kd + base);
            async_ld16(vsub + base + lane * 16, vd + base);
        }
        const unsigned char* kb = Ks[p & 1];
        const unsigned char* vb = Vs[p & 1];
        f32x4 st[2] = {};
#pragma unroll
        for (int nt = 0; nt < 2; ++nt) {
#pragma unroll
            for (int ks = 0; ks < 16; ++ks) {
                long kf = *(const long*)&kb[(ks * 4 + quad) * 256 + (nt * 16 + l15) * 8];
                st[nt] = __builtin_amdgcn_mfma_f32_16x16x32_fp8_fp8(qf[ks], kf, st[nt], 0, 0, 0);
            }
        }
        float p0[4], p1[4];
#pragma unroll
        for (int rg = 0; rg < 4; ++rg) {
            p0[rg] = __expf(st[0][rg] * scale);
            p1[rg] = __expf(st[1][rg] * scale);
            l_i[rg] += p0[rg] + p1[rg];
        }
        unsigned char* pw = Ps[wave];
#pragma unroll
        for (int rg = 0; rg < 4; ++rg) {
            pw[(quad * 4 + rg) * 40 + l15] = to_fp8(p0[rg]);
            pw[(quad * 4 + rg) * 40 + 16 + l15] = to_fp8(p1[rg]);
        }
        long pf = *(const long*)&pw[l15 * 40 + quad * 8];
#pragma unroll
        for (int dn = 0; dn < 32; ++dn) {
            long vf = *(const long*)&vb[quad * 4096 + (dn * 16 + l15) * 8];
            oacc[dn] = __builtin_amdgcn_mfma_f32_16x16x32_fp8_fp8(pf, vf, oacc[dn], 0, 0, 0);
        }
        __syncthreads();
    }
#pragma unroll
    for (int rg = 0; rg < 4; ++rg)
        for (int d = 1; d < 16; d <<= 1)
            l_i[rg] += __shfl_xor(l_i[rg], d);
    float rinv[4];
#pragma unroll
    for (int rg = 0; rg < 4; ++rg) rinv[rg] = 1.f / l_i[rg];
    bf16* op = ob + (size_t)(b * S_DIM + qbase) * C_DIM;
#pragma unroll
    for (int dn = 0; dn < 32; ++dn)
#pragma unroll
        for (int rg = 0; rg < 4; ++rg)
            op[(size_t)(quad * 4 + rg) * C_DIM + dn * 16 + l15] =
                (bf16)(oacc[dn][rg] * rinv[rg]);
}

// ------------- Kernel 5: split-K combine (slot-list weighted sum) --------
__global__ __launch_bounds__(256) void combine_kernel(const bf16* __restrict__ part,
                                                      const float* __restrict__ lsum,
                                                      bf16* __restrict__ ob,
                                                      const int* __restrict__ cnt,
                                                      const int* __restrict__ slist) {
    int id = blockIdx.x;            // q-tile ordinal 0..255
    int b  = id >> 7;
    int q0 = (id & 127) * 64;
    int U  = cnt[id];               // 1..~5 segments
    int qq = threadIdx.x >> 2;      // 0..63
    int cr = threadIdx.x & 3;       // 128-ch segment
    int sl[8];
    float w[8];
    float D = 0.f;
    for (int u = 0; u < U; ++u) {
        sl[u] = slist[id * 8 + u];
        w[u] = lsum[sl[u] * 64 + qq];
        D += w[u];
    }
    float Dinv = 1.f / D;
    for (int u = 0; u < U; ++u) w[u] *= Dinv;
    bf16* op = ob + (size_t)(b * S_DIM + q0 + qq) * C_DIM + cr * 128;
    for (int ch = 0; ch < 16; ++ch) {
        float acc[8] = {};
        for (int u = 0; u < U; ++u) {
            bf16x8 pv = *(const bf16x8*)&part[((size_t)sl[u] * 64 + qq) * C_DIM + cr * 128 + ch * 8];
#pragma unroll
            for (int j = 0; j < 8; ++j) acc[j] += w[u] * (float)pv[j];
        }
        bf16x8 o8;
#pragma unroll
        for (int j = 0; j < 8; ++j) o8[j] = (bf16)acc[j];
        *(bf16x8*)&op[ch * 8] = o8;
    }
}

extern "C" void kernel_launch(void* const* d_in, const int* in_sizes, int n_in,
                              void* d_out, int out_size, void* d_ws, size_t ws_size,
                              hipStream_t stream) {
    const void* x     = d_in[0];
    const void* gamma = d_in[1];
    const void* wq    = d_in[2];
    const void* bq    = d_in[3];
    const void* wk    = d_in[4];
    const void* bk    = d_in[5];
    const void* wv    = d_in[6];
    const void* bv    = d_in[7];
    const void* wo    = d_in[8];
    const void* bo    = d_in[9];

    char* ws = (char*)d_ws;
    int*   flag    = (int*)ws;                 // [0]=flag, [16]=slot counter, [64..320)=cnt
    int*   counter = (int*)(ws + 64);
    int*   cntp    = (int*)(ws + 256);
    int*   slist   = (int*)(ws + 0x12000);     // 256 q-tiles x 8 slots (8 KB)
    float* r_buf   = (float*)(ws + 4096);
    bf16* wqb = (bf16*)(ws + 0x20000);   // 4 weights contiguous, 512 KB each
    bf16* wkb = (bf16*)(ws + 0xA0000);
    bf16* wvb = (bf16*)(ws + 0x120000);
    bf16* wob = (bf16*)(ws + 0x1A0000);
    float* lsum_buf = (float*)(ws + 0x240000);                  // <=768 slots x 64 f32
    bf16* hn  = (bf16*)(ws + 0x400000);                         // 16 MB
    unsigned char* qb  = (unsigned char*)(ws + 0x1400000);      // 8 MB (fp8)
    unsigned char* kb  = (unsigned char*)(ws + 0x1C00000);      // 8 MB
    unsigned char* vtb = (unsigned char*)(ws + 0x2400000);      // 8 MB
    bf16* ob  = (bf16*)(ws + 0x2C00000);                        // 16 MB
    bf16* part = (bf16*)(ws + 0x5400000);                       // <=768 slots x 64 x 512 bf16 (50.3 MB)

    const size_t ws_needed_split = 0x5400000ull + 768ull * 64 * 512 * 2;
    int split = (ws_size >= ws_needed_split) ? 1 : 0;

    hipLaunchKernelGGL(detect_kernel, dim3(1), dim3(64), 0, stream,
                       (const unsigned short*)x, flag);
    hipLaunchKernelGGL(convert_kernel, dim3(1024, 4), dim3(256), 0, stream,
                       wq, wk, wv, wo, wqb, flag);
    hipLaunchKernelGGL(rms_kernel, dim3(256), dim3(256), 0, stream, x, r_buf, flag);
    hipLaunchKernelGGL(hn_kernel, dim3(128, 8, 2), dim3(256), 0, stream, x, gamma, r_buf, hn, flag);
    hipLaunchKernelGGL(gemm_kernel, dim3(128, 4), dim3(256), 0, stream, hn, wqb, bq, (const void*)nullptr, qb, 0, flag);
    hipLaunchKernelGGL(gemm_kernel, dim3(128, 4), dim3(256), 0, stream, hn, wkb, bk, (const void*)nullptr, kb, 3, flag);
    hipLaunchKernelGGL(gemm_kernel, dim3(128, 4), dim3(256), 0, stream, hn, wvb, bv, (const void*)nullptr, vtb, 1, flag);
    if (split) {
        hipLaunchKernelGGL(attn_split_kernel, dim3(256), dim3(512), 0, stream,
                           qb, kb, vtb, part, lsum_buf, counter, cntp, slist);
        hipLaunchKernelGGL(combine_kernel, dim3(256), dim3(256), 0, stream,
                           part, lsum_buf, ob, cntp, slist);
    } else {
        hipLaunchKernelGGL(attn_kernel, dim3(256), dim3(256), 0, stream, qb, kb, vtb, ob);
    }
    hipLaunchKernelGGL(gemm_kernel, dim3(128, 4), dim3(256), 0, stream, ob, wob, bo, x, d_out, 2, flag);
}

// Round 3
// 382.399 us; speedup vs baseline: 1.1663x; 1.1663x over previous
//
#include <hip/hip_runtime.h>
#include <hip/hip_bf16.h>
#include <math.h>

typedef __bf16 bf16;
typedef __bf16 bf16x8 __attribute__((ext_vector_type(8)));
typedef float f32x4 __attribute__((ext_vector_type(4)));

#define C_DIM 512
#define S_DIM 8192

__device__ __forceinline__ void async_ld16(const void* g, void* l) {
    __builtin_amdgcn_global_load_lds(
        (const __attribute__((address_space(1))) unsigned int*)g,
        (__attribute__((address_space(3))) unsigned int*)l, 16, 0, 0);
}

// f32 -> OCP e4m3 via HW cvt (gfx950: v_cvt_pk_fp8_f32 emits OCP format)
__device__ __forceinline__ unsigned char to_fp8(float v) {
    return (unsigned char)(__builtin_amdgcn_cvt_pk_fp8_f32(v, v, 0, false) & 0xFF);
}

// ---------------- Kernel 0: dtype detect (wave ballot) + aux zeroing -----
// flag[0] = dtype flag; flag[16] = slot counter; flag[64..320) = cnt[256]
__global__ void detect_kernel(const unsigned short* __restrict__ xu, int* __restrict__ flag) {
    int j = threadIdx.x;   // 64 threads
    for (int i = 16 + j; i < 320; i += 64) flag[i] = 0;   // zero counter + cnt[256]
    unsigned e = (xu[2 * j] >> 7) & 0xFF;
    unsigned long long m = __ballot(e >= 90 && e <= 140);
    if (j == 0) *flag = (__popcll(m) >= 48) ? 1 : 0;   // 1 = bf16, 0 = fp32
}

// ---------------- Kernel 0b: all 4 weights -> bf16 (one launch) ----------
__global__ __launch_bounds__(256) void convert_kernel(const void* __restrict__ s0,
                                                      const void* __restrict__ s1,
                                                      const void* __restrict__ s2,
                                                      const void* __restrict__ s3,
                                                      bf16* __restrict__ dst,
                                                      const int* __restrict__ flag) {
    int y = blockIdx.y;
    const void* srcs[4] = {s0, s1, s2, s3};
    const void* src = srcs[y];
    int i = blockIdx.x * 256 + threadIdx.x;
    bf16* d = dst + (size_t)y * 262144;
    if (*flag) {
        volatile const bf16* s = (volatile const bf16*)src;
        d[i] = s[i];
    } else {
        volatile const float* s = (volatile const float*)src;
        d[i] = (bf16)s[i];
    }
}

// ---------------- Kernel 1: per-token inverse RMS norm (coalesced) -------
__global__ __launch_bounds__(256) void rms_kernel(const void* __restrict__ x,
                                                  float* __restrict__ r,
                                                  const int* __restrict__ flag) {
    __shared__ float red[4][64];
    int b  = blockIdx.x >> 7;
    int s0 = (blockIdx.x & 127) * 64;
    int sl = threadIdx.x & 63;
    int cq = threadIdx.x >> 6;   // 0..3 -> 128-channel slab
    float acc = 0.f;
    if (*flag) {
        const bf16* xp = (const bf16*)x + ((size_t)b * C_DIM + cq * 128) * S_DIM + s0 + sl;
        for (int c = 0; c < 128; ++c) { float v = (float)xp[(size_t)c * S_DIM]; acc += v * v; }
    } else {
        const float* xp = (const float*)x + ((size_t)b * C_DIM + cq * 128) * S_DIM + s0 + sl;
        for (int c = 0; c < 128; ++c) { float v = xp[(size_t)c * S_DIM]; acc += v * v; }
    }
    red[cq][sl] = acc;
    __syncthreads();
    if (cq == 0) {
        float t = red[0][sl] + red[1][sl] + red[2][sl] + red[3][sl];
        r[b * S_DIM + s0 + sl] = 22.627416997969522f / fmaxf(sqrtf(t), 1e-12f);
    }
}

// ------------- Kernel 2: transpose+scale -> hn[b][s][c] (token-major) ----
__global__ __launch_bounds__(256) void hn_kernel(const void* __restrict__ x,
                                                 const void* __restrict__ gamma,
                                                 const float* __restrict__ r,
                                                 bf16* __restrict__ hn,
                                                 const int* __restrict__ flag) {
    __shared__ float tile[64][65];
    int f  = *flag;
    int b  = blockIdx.z;
    int c0 = blockIdx.y * 64;
    int s0 = blockIdx.x * 64;
    int col = threadIdx.x & 63;
    int row = threadIdx.x >> 6;
    if (f) {
        const bf16* xp = (const bf16*)x + ((size_t)b * C_DIM + c0) * S_DIM + s0;
        for (int i = 0; i < 16; ++i)
            tile[row + i * 4][col] = (float)xp[(size_t)(row + i * 4) * S_DIM + col];
    } else {
        const float* xp = (const float*)x + ((size_t)b * C_DIM + c0) * S_DIM + s0;
        for (int i = 0; i < 16; ++i)
            tile[row + i * 4][col] = xp[(size_t)(row + i * 4) * S_DIM + col];
    }
    __syncthreads();
    float g;
    if (f) g = (float)((const bf16*)gamma)[c0 + col];
    else   g = ((const float*)gamma)[c0 + col];
    bf16* hp = hn + ((size_t)b * S_DIM + s0) * C_DIM + c0;
    for (int i = 0; i < 16; ++i) {
        int s_l = row + i * 4;
        float rv = r[b * S_DIM + s0 + s_l];
        hp[(size_t)s_l * C_DIM + col] = (bf16)(tile[col][s_l] * rv * g);
    }
}

// ------------- Kernel 3a: fused QKV GEMM --------------------------------
// One A-tile staging feeds three weight tiles: 48 MFMA per 32-K step.
// out q: fp8 token-major [m][n]
// out k: fp8 K-frag tiled [b][s/32][kcg64][key32][kch8]
// out v: fp8 V-frag tiled [b][s/32][kq4][ch512][k8]
__global__ __launch_bounds__(256, 2) void gemm_qkv_kernel(const bf16* __restrict__ A,
                                                          const bf16* __restrict__ Wq,
                                                          const bf16* __restrict__ Wk,
                                                          const bf16* __restrict__ Wv,
                                                          const void* __restrict__ bq,
                                                          const void* __restrict__ bk,
                                                          const void* __restrict__ bv,
                                                          unsigned char* __restrict__ oq,
                                                          unsigned char* __restrict__ ok,
                                                          unsigned char* __restrict__ ov,
                                                          const int* __restrict__ flag) {
    __shared__ bf16 As[128 * 40];
    __shared__ bf16 Bqs[128 * 40];
    __shared__ bf16 Bks[128 * 40];
    __shared__ bf16 Bvs[128 * 40];
    int f  = *flag;
    int m0 = blockIdx.x * 128;
    int n0 = blockIdx.y * 128;
    int tid  = threadIdx.x;
    int lane = tid & 63;
    int wave = tid >> 6;
    int wm = (wave & 1) * 64;
    int wn = (wave >> 1) * 64;
    int l15  = lane & 15;
    int quad = lane >> 4;

    f32x4 aq[4][4] = {}, ak[4][4] = {}, av[4][4] = {};
    for (int k0 = 0; k0 < C_DIM; k0 += 32) {
        __syncthreads();
        for (int u = tid; u < 512; u += 256) {
            int rr = u >> 2;
            int cc = (u & 3) * 8;
            *(bf16x8*)&As[rr * 40 + cc]  = *(const bf16x8*)&A [(size_t)(m0 + rr) * C_DIM + k0 + cc];
            *(bf16x8*)&Bqs[rr * 40 + cc] = *(const bf16x8*)&Wq[(size_t)(n0 + rr) * C_DIM + k0 + cc];
            *(bf16x8*)&Bks[rr * 40 + cc] = *(const bf16x8*)&Wk[(size_t)(n0 + rr) * C_DIM + k0 + cc];
            *(bf16x8*)&Bvs[rr * 40 + cc] = *(const bf16x8*)&Wv[(size_t)(n0 + rr) * C_DIM + k0 + cc];
        }
        __syncthreads();
        bf16x8 af[4];
#pragma unroll
        for (int i = 0; i < 4; ++i)
            af[i] = *(bf16x8*)&As[(wm + i * 16 + l15) * 40 + quad * 8];
#pragma unroll
        for (int j = 0; j < 4; ++j) {
            int boff = (wn + j * 16 + l15) * 40 + quad * 8;
            bf16x8 b0 = *(bf16x8*)&Bqs[boff];
#pragma unroll
            for (int i = 0; i < 4; ++i)
                aq[i][j] = __builtin_amdgcn_mfma_f32_16x16x32_bf16(af[i], b0, aq[i][j], 0, 0, 0);
            bf16x8 b1 = *(bf16x8*)&Bks[boff];
#pragma unroll
            for (int i = 0; i < 4; ++i)
                ak[i][j] = __builtin_amdgcn_mfma_f32_16x16x32_bf16(af[i], b1, ak[i][j], 0, 0, 0);
            bf16x8 b2 = *(bf16x8*)&Bvs[boff];
#pragma unroll
            for (int i = 0; i < 4; ++i)
                av[i][j] = __builtin_amdgcn_mfma_f32_16x16x32_bf16(af[i], b2, av[i][j], 0, 0, 0);
        }
    }
#pragma unroll
    for (int i = 0; i < 4; ++i)
#pragma unroll
        for (int j = 0; j < 4; ++j) {
            int n = n0 + wn + j * 16 + l15;
            float bvq = f ? (float)((const bf16*)bq)[n] : ((const float*)bq)[n];
            float bvk = f ? (float)((const bf16*)bk)[n] : ((const float*)bk)[n];
            float bvv = f ? (float)((const bf16*)bv)[n] : ((const float*)bv)[n];
#pragma unroll
            for (int rg = 0; rg < 4; ++rg) {
                int m = m0 + wm + i * 16 + quad * 4 + rg;
                // q: token-major
                oq[(size_t)m * C_DIM + n] = to_fp8(aq[i][j][rg] + bvq);
                // k: frag tiled
                size_t ik = ((((size_t)(m >> 5) * 64 + (n >> 3)) * 32 + (m & 31)) * 8) + (n & 7);
                ok[ik] = to_fp8(ak[i][j][rg] + bvk);
                // v: frag tiled
                size_t iv = ((((size_t)(m >> 5) * 4 + ((m >> 3) & 3)) * 512 + n) * 8) + (m & 7);
                ov[iv] = to_fp8(av[i][j][rg] + bvv);
            }
        }
}

// ------------- Kernel 3b: output GEMM  out = A.Wo + bias + resid ---------
__global__ __launch_bounds__(256, 2) void gemm_kernel(const bf16* __restrict__ A,
                                                      const bf16* __restrict__ W,
                                                      const void* __restrict__ bias,
                                                      const void* __restrict__ resid,
                                                      void* __restrict__ out,
                                                      const int* __restrict__ flag) {
    __shared__ bf16 As[128 * 40];
    __shared__ bf16 Bs[128 * 40];
    int f  = *flag;
    int m0 = blockIdx.x * 128;
    int n0 = blockIdx.y * 128;
    int tid  = threadIdx.x;
    int lane = tid & 63;
    int wave = tid >> 6;
    int wm = (wave & 1) * 64;
    int wn = (wave >> 1) * 64;
    int l15  = lane & 15;
    int quad = lane >> 4;

    f32x4 acc[4][4] = {};
    for (int k0 = 0; k0 < C_DIM; k0 += 32) {
        __syncthreads();
        for (int u = tid; u < 512; u += 256) {
            int rrow = u >> 2;
            int cc = (u & 3) * 8;
            *(bf16x8*)&As[rrow * 40 + cc] =
                *(const bf16x8*)&A[(size_t)(m0 + rrow) * C_DIM + k0 + cc];
            *(bf16x8*)&Bs[rrow * 40 + cc] =
                *(const bf16x8*)&W[(size_t)(n0 + rrow) * C_DIM + k0 + cc];
        }
        __syncthreads();
        bf16x8 af[4], bfr[4];
#pragma unroll
        for (int i = 0; i < 4; ++i)
            af[i] = *(bf16x8*)&As[(wm + i * 16 + l15) * 40 + quad * 8];
#pragma unroll
        for (int j = 0; j < 4; ++j)
            bfr[j] = *(bf16x8*)&Bs[(wn + j * 16 + l15) * 40 + quad * 8];
#pragma unroll
        for (int i = 0; i < 4; ++i)
#pragma unroll
            for (int j = 0; j < 4; ++j)
                acc[i][j] = __builtin_amdgcn_mfma_f32_16x16x32_bf16(af[i], bfr[j], acc[i][j], 0, 0, 0);
    }
    if (f) {
        bf16* op = (bf16*)out;
        const bf16* rp = (const bf16*)resid;
#pragma unroll
        for (int i = 0; i < 4; ++i)
#pragma unroll
            for (int j = 0; j < 4; ++j)
#pragma unroll
                for (int rg = 0; rg < 4; ++rg) {
                    int m = m0 + wm + i * 16 + quad * 4 + rg;
                    int n = n0 + wn + j * 16 + l15;
                    float bv = (float)((const bf16*)bias)[n];
                    int b = m >> 13, s = m & 8191;
                    size_t idx = ((size_t)b * C_DIM + n) * S_DIM + s;
                    op[idx] = (bf16)(acc[i][j][rg] + bv + (float)rp[idx]);
                }
    } else {
        float* op = (float*)out;
        const float* rp = (const float*)resid;
#pragma unroll
        for (int i = 0; i < 4; ++i)
#pragma unroll
            for (int j = 0; j < 4; ++j)
#pragma unroll
                for (int rg = 0; rg < 4; ++rg) {
                    int m = m0 + wm + i * 16 + quad * 4 + rg;
                    int n = n0 + wn + j * 16 + l15;
                    float bv = ((const float*)bias)[n];
                    int b = m >> 13, s = m & 8191;
                    size_t idx = ((size_t)b * C_DIM + n) * S_DIM + s;
                    op[idx] = acc[i][j][rg] + bv + rp[idx];
                }
    }
}

// ------------- Kernel 4a: balanced split flash attention (round-1 winner)
// 512 blocks x 256 threads, 2 blocks/CU desynchronized (mutual stall
// hiding), 72 key-chunks per block = exactly one balanced round.
__global__ __launch_bounds__(256, 2) void attn_split_kernel(const unsigned char* __restrict__ q,
                                                            const unsigned char* __restrict__ k,
                                                            const unsigned char* __restrict__ vt,
                                                            bf16* __restrict__ part,
                                                            float* __restrict__ lsum,
                                                            int* __restrict__ counter,
                                                            int* __restrict__ cnt,
                                                            int* __restrict__ slist) {
    __shared__ unsigned char Ks[2][16384];   // 32 KB
    __shared__ unsigned char Vs[2][16384];   // 32 KB
    __shared__ unsigned char Ps[4][16 * 40]; // 2.5 KB
    __shared__ int slot_sh;
    int tid  = threadIdx.x;
    int lane = tid & 63;
    int wave = tid >> 6;
    int l15  = lane & 15;
    int quad = lane >> 4;

    // ---- decode start state for g0 = 72*blockIdx (uniform scalar) ----
    // per-batch: frame f starts at chunk 256*f*(f+1); tile length L=32*(f+1)
    int g0 = blockIdx.x * 72;
    int b_ = (g0 >= 18432) ? 1 : 0;
    int r  = g0 - b_ * 18432;
    int f_ = 0;
    while (r >= 256 * (f_ + 1) * (f_ + 2)) ++f_;
    int L   = 32 * (f_ + 1);
    int rr  = r - 256 * f_ * (f_ + 1);
    int tif = rr / L;
    int cw  = rr - tif * L;          // key-chunk within tile == absolute key chunk

    // ---- Q fragments for current tile (16 K-steps over C=512) ----
    long qf[16];
    {
        int qbase = (f_ * 16 + tif) * 64 + wave * 16;
        const unsigned char* qp = q + (size_t)(b_ * S_DIM + qbase + l15) * C_DIM;
#pragma unroll
        for (int ks = 0; ks < 16; ++ks)
            qf[ks] = *(const long*)&qp[ks * 32 + quad * 8];
    }

    f32x4 oacc[32] = {};
    float l_i[4] = {0.f, 0.f, 0.f, 0.f};
    const float scale = 0.044194173824159216f;  // 1/sqrt(512)

    // prefetch chunk 0 into buffer 0 (wave-uniform LDS base + lane*16)
    {
        const unsigned char* ka = k  + ((size_t)(b_ * 256 + cw) << 14);
        const unsigned char* va = vt + ((size_t)(b_ * 256 + cw) << 14);
#pragma unroll
        for (int j = 0; j < 4; ++j) {
            int base = (j * 4 + wave) * 1024;
            async_ld16(ka + base + lane * 16, &Ks[0][base]);
            async_ld16(va + base + lane * 16, &Vs[0][base]);
        }
    }
    __syncthreads();

    for (int i = 0; i < 72; ++i) {
        // ---- advance to next-state (scalar); last iter re-fetches current ----
        int last = (i == 71);
        int nb = b_, nf = f_, nL = L, ntif = tif, ncw = cw + 1;
        int newtile = 0;
        if (ncw == L) {
            ncw = 0; newtile = 1; ntif = tif + 1;
            if (ntif == 16) {
                ntif = 0; nf = f_ + 1; nL = L + 32;
                if (nf == 8) { nf = 0; nL = 32; nb = b_ + 1; }
            }
        }
        if (last) { nb = b_; nf = f_; nL = L; ntif = tif; ncw = cw; newtile = 0; }

        // ---- prefetch next chunk into the other buffer ----
        {
            const unsigned char* ka = k  + ((size_t)(nb * 256 + ncw) << 14);
            const unsigned char* va = vt + ((size_t)(nb * 256 + ncw) << 14);
            unsigned char* kd = Ks[(i + 1) & 1];
            unsigned char* vd = Vs[(i + 1) & 1];
#pragma unroll
            for (int j = 0; j < 4; ++j) {
                int base = (j * 4 + wave) * 1024;
                async_ld16(ka + base + lane * 16, kd + base);
                async_ld16(va + base + lane * 16, vd + base);
            }
        }
        const unsigned char* kb = Ks[i & 1];
        const unsigned char* vb = Vs[i & 1];
        // S = q . k^T  (two 16-key sub-tiles); kf: 8 B at (ks*4+quad)*256+key*8
        f32x4 st[2] = {};
#pragma unroll
        for (int nt = 0; nt < 2; ++nt) {
#pragma unroll
            for (int ks = 0; ks < 16; ++ks) {
                long kf = *(const long*)&kb[(ks * 4 + quad) * 256 + (nt * 16 + l15) * 8];
                st[nt] = __builtin_amdgcn_mfma_f32_16x16x32_fp8_fp8(qf[ks], kf, st[nt], 0, 0, 0);
            }
        }
        // softmax-lite: raw exp (scores bounded), per-lane l accumulation
        float p0[4], p1[4];
#pragma unroll
        for (int rg = 0; rg < 4; ++rg) {
            p0[rg] = __expf(st[0][rg] * scale);
            p1[rg] = __expf(st[1][rg] * scale);
            l_i[rg] += p0[rg] + p1[rg];
        }
        // P (C layout) -> per-wave fp8 LDS scratch -> A layout (same-wave)
        unsigned char* pw = Ps[wave];
#pragma unroll
        for (int rg = 0; rg < 4; ++rg) {
            pw[(quad * 4 + rg) * 40 + l15] = to_fp8(p0[rg]);
            pw[(quad * 4 + rg) * 40 + 16 + l15] = to_fp8(p1[rg]);
        }
        long pf = *(const long*)&pw[l15 * 40 + quad * 8];
        // PV: vf 8 B at quad*4096 + ch*8
#pragma unroll
        for (int dn = 0; dn < 32; ++dn) {
            long vf = *(const long*)&vb[quad * 4096 + (dn * 16 + l15) * 8];
            oacc[dn] = __builtin_amdgcn_mfma_f32_16x16x32_fp8_fp8(pf, vf, oacc[dn], 0, 0, 0);
        }

        // ---- flush segment at tile boundary / end of span ----
        if (last || newtile) {
            int ord = b_ * 128 + f_ * 16 + tif;   // q-tile ordinal 0..255
            if (tid == 0) {
                int s = atomicAdd(counter, 1);
                int pos = atomicAdd(&cnt[ord], 1);
                slist[ord * 8 + pos] = s;
                slot_sh = s;
            }
            __syncthreads();
            int slot = slot_sh;
            // reduce l across the 16 key-lanes
#pragma unroll
            for (int rg = 0; rg < 4; ++rg)
                for (int d = 1; d < 16; d <<= 1)
                    l_i[rg] += __shfl_xor(l_i[rg], d);
            float rinv[4];
#pragma unroll
            for (int rg = 0; rg < 4; ++rg) rinv[rg] = 1.f / l_i[rg];
            bf16* pp = part + ((size_t)slot * 64 + wave * 16) * C_DIM;
#pragma unroll
            for (int dn = 0; dn < 32; ++dn)
#pragma unroll
                for (int rg = 0; rg < 4; ++rg)
                    pp[(size_t)(quad * 4 + rg) * C_DIM + dn * 16 + l15] =
                        (bf16)(oacc[dn][rg] * rinv[rg]);
            if (l15 == 0) {
#pragma unroll
                for (int rg = 0; rg < 4; ++rg)
                    lsum[slot * 64 + wave * 16 + quad * 4 + rg] = l_i[rg];
            }
            if (!last) {
                // reset accumulators, reload Q for the next tile
#pragma unroll
                for (int dn = 0; dn < 32; ++dn) oacc[dn] = (f32x4){0.f, 0.f, 0.f, 0.f};
#pragma unroll
                for (int rg = 0; rg < 4; ++rg) l_i[rg] = 0.f;
                int nqbase = (nf * 16 + ntif) * 64 + wave * 16;
                const unsigned char* qp = q + (size_t)(nb * S_DIM + nqbase + l15) * C_DIM;
#pragma unroll
                for (int ks = 0; ks < 16; ++ks)
                    qf[ks] = *(const long*)&qp[ks * 32 + quad * 8];
            }
        }
        b_ = nb; f_ = nf; L = nL; tif = ntif; cw = ncw;
        __syncthreads();   // drains prefetch + all waves done with buffers
    }
}

// ------------- Kernel 4b: non-split fallback flash attention -------------
__global__ __launch_bounds__(256, 2) void attn_kernel(const unsigned char* __restrict__ q,
                                                      const unsigned char* __restrict__ k,
                                                      const unsigned char* __restrict__ vt,
                                                      bf16* __restrict__ ob) {
    __shared__ unsigned char Ks[2][16384];
    __shared__ unsigned char Vs[2][16384];
    __shared__ unsigned char Ps[4][16 * 40];
    int id = blockIdx.x;
    int b = id >> 7;
    int t = id & 127;
    int q0 = t * 64;
    int kc1 = ((t >> 4) + 1) << 10;
    int tid  = threadIdx.x;
    int lane = tid & 63;
    int wave = tid >> 6;
    int l15  = lane & 15;
    int quad = lane >> 4;
    int qbase = q0 + wave * 16;
    int nchunks = kc1 >> 5;

    long qf[16];
    const unsigned char* qp = q + (size_t)(b * S_DIM + qbase + l15) * C_DIM;
#pragma unroll
    for (int ks = 0; ks < 16; ++ks)
        qf[ks] = *(const long*)&qp[ks * 32 + quad * 8];

    f32x4 oacc[32] = {};
    float l_i[4] = {0.f, 0.f, 0.f, 0.f};
    const float scale = 0.044194173824159216f;

    const unsigned char* kbase = k  + ((size_t)(b * 256) << 14);
    const unsigned char* vbase = vt + ((size_t)(b * 256) << 14);

#pragma unroll
    for (int j = 0; j < 4; ++j) {
        int base = (j * 4 + wave) * 1024;
        async_ld16(kbase + base + lane * 16, &Ks[0][base]);
        async_ld16(vbase + base + lane * 16, &Vs[0][base]);
    }
    __syncthreads();

    for (int p = 0; p < nchunks; ++p) {
        int pn = (p + 1 < nchunks) ? (p + 1) : p;
        const unsigned char* ksub = kbase + ((size_t)pn << 14);
        const unsigned char* vsub = vbase + ((size_t)pn << 14);
        unsigned char* kd = Ks[(p + 1) & 1];
        unsigned char* vd = Vs[(p + 1) & 1];
#pragma unroll
        for (int j = 0; j < 4; ++j) {
            int base = (j * 4 + wave) * 1024;
            async_ld16(ksub + base + lane * 16, kd + base);
            async_ld16(vsub + base + lane * 16, vd + base);
        }
        const unsigned char* kb = Ks[p & 1];
        const unsigned char* vb = Vs[p & 1];
        f32x4 st[2] = {};
#pragma unroll
        for (int nt = 0; nt < 2; ++nt) {
#pragma unroll
            for (int ks = 0; ks < 16; ++ks) {
                long kf = *(const long*)&kb[(ks * 4 + quad) * 256 + (nt * 16 + l15) * 8];
                st[nt] = __builtin_amdgcn_mfma_f32_16x16x32_fp8_fp8(qf[ks], kf, st[nt], 0, 0, 0);
            }
        }
        float p0[4], p1[4];
#pragma unroll
        for (int rg = 0; rg < 4; ++rg) {
            p0[rg] = __expf(st[0][rg] * scale);
            p1[rg] = __expf(st[1][rg] * scale);
            l_i[rg] += p0[rg] + p1[rg];
        }
        unsigned char* pw = Ps[wave];
#pragma unroll
        for (int rg = 0; rg < 4; ++rg) {
            pw[(quad * 4 + rg) * 40 + l15] = to_fp8(p0[rg]);
            pw[(quad * 4 + rg) * 40 + 16 + l15] = to_fp8(p1[rg]);
        }
        long pf = *(const long*)&pw[l15 * 40 + quad * 8];
#pragma unroll
        for (int dn = 0; dn < 32; ++dn) {
            long vf = *(const long*)&vb[quad * 4096 + (dn * 16 + l15) * 8];
            oacc[dn] = __builtin_amdgcn_mfma_f32_16x16x32_fp8_fp8(pf, vf, oacc[dn], 0, 0, 0);
        }
        __syncthreads();
    }
#pragma unroll
    for (int rg = 0; rg < 4; ++rg)
        for (int d = 1; d < 16; d <<= 1)
            l_i[rg] += __shfl_xor(l_i[rg], d);
    float rinv[4];
#pragma unroll
    for (int rg = 0; rg < 4; ++rg) rinv[rg] = 1.f / l_i[rg];
    bf16* op = ob + (size_t)(b * S_DIM + qbase) * C_DIM;
#pragma unroll
    for (int dn = 0; dn < 32; ++dn)
#pragma unroll
        for (int rg = 0; rg < 4; ++rg)
            op[(size_t)(quad * 4 + rg) * C_DIM + dn * 16 + l15] =
                (bf16)(oacc[dn][rg] * rinv[rg]);
}

// ------------- Kernel 5: split-K combine (slot-list weighted sum) --------
__global__ __launch_bounds__(256) void combine_kernel(const bf16* __restrict__ part,
                                                      const float* __restrict__ lsum,
                                                      bf16* __restrict__ ob,
                                                      const int* __restrict__ cnt,
                                                      const int* __restrict__ slist) {
    int id = blockIdx.x;            // q-tile ordinal 0..255
    int b  = id >> 7;
    int q0 = (id & 127) * 64;
    int U  = cnt[id];               // 1..~5 segments
    int qq = threadIdx.x >> 2;      // 0..63
    int cr = threadIdx.x & 3;       // 128-ch segment
    int sl[8];
    float w[8];
    float D = 0.f;
    for (int u = 0; u < U; ++u) {
        sl[u] = slist[id * 8 + u];
        w[u] = lsum[sl[u] * 64 + qq];
        D += w[u];
    }
    float Dinv = 1.f / D;
    for (int u = 0; u < U; ++u) w[u] *= Dinv;
    bf16* op = ob + (size_t)(b * S_DIM + q0 + qq) * C_DIM + cr * 128;
    for (int ch = 0; ch < 16; ++ch) {
        float acc[8] = {};
        for (int u = 0; u < U; ++u) {
            bf16x8 pv = *(const bf16x8*)&part[((size_t)sl[u] * 64 + qq) * C_DIM + cr * 128 + ch * 8];
#pragma unroll
            for (int j = 0; j < 8; ++j) acc[j] += w[u] * (float)pv[j];
        }
        bf16x8 o8;
#pragma unroll
        for (int j = 0; j < 8; ++j) o8[j] = (bf16)acc[j];
        *(bf16x8*)&op[ch * 8] = o8;
    }
}

extern "C" void kernel_launch(void* const* d_in, const int* in_sizes, int n_in,
                              void* d_out, int out_size, void* d_ws, size_t ws_size,
                              hipStream_t stream) {
    const void* x     = d_in[0];
    const void* gamma = d_in[1];
    const void* wq    = d_in[2];
    const void* bq    = d_in[3];
    const void* wk    = d_in[4];
    const void* bk    = d_in[5];
    const void* wv    = d_in[6];
    const void* bv    = d_in[7];
    const void* wo    = d_in[8];
    const void* bo    = d_in[9];

    char* ws = (char*)d_ws;
    int*   flag    = (int*)ws;                 // [0]=flag, [16]=slot counter, [64..320)=cnt
    int*   counter = (int*)(ws + 64);
    int*   cntp    = (int*)(ws + 256);
    int*   slist   = (int*)(ws + 0x12000);     // 256 q-tiles x 8 slots (8 KB)
    float* r_buf   = (float*)(ws + 4096);
    bf16* wqb = (bf16*)(ws + 0x20000);   // 4 weights contiguous, 512 KB each
    bf16* wkb = (bf16*)(ws + 0xA0000);
    bf16* wvb = (bf16*)(ws + 0x120000);
    bf16* wob = (bf16*)(ws + 0x1A0000);
    float* lsum_buf = (float*)(ws + 0x240000);                  // <=768 slots x 64 f32
    bf16* hn  = (bf16*)(ws + 0x400000);                         // 16 MB
    unsigned char* qb  = (unsigned char*)(ws + 0x1400000);      // 8 MB (fp8)
    unsigned char* kb  = (unsigned char*)(ws + 0x1C00000);      // 8 MB
    unsigned char* vtb = (unsigned char*)(ws + 0x2400000);      // 8 MB
    bf16* ob  = (bf16*)(ws + 0x2C00000);                        // 16 MB
    bf16* part = (bf16*)(ws + 0x5400000);                       // <=768 slots x 64 x 512 bf16 (50.3 MB)

    const size_t ws_needed_split = 0x5400000ull + 768ull * 64 * 512 * 2;
    int split = (ws_size >= ws_needed_split) ? 1 : 0;

    hipLaunchKernelGGL(detect_kernel, dim3(1), dim3(64), 0, stream,
                       (const unsigned short*)x, flag);
    hipLaunchKernelGGL(convert_kernel, dim3(1024, 4), dim3(256), 0, stream,
                       wq, wk, wv, wo, wqb, flag);
    hipLaunchKernelGGL(rms_kernel, dim3(256), dim3(256), 0, stream, x, r_buf, flag);
    hipLaunchKernelGGL(hn_kernel, dim3(128, 8, 2), dim3(256), 0, stream, x, gamma, r_buf, hn, flag);
    hipLaunchKernelGGL(gemm_qkv_kernel, dim3(128, 4), dim3(256), 0, stream,
                       hn, wqb, wkb, wvb, bq, bk, bv, qb, kb, vtb, flag);
    if (split) {
        hipLaunchKernelGGL(attn_split_kernel, dim3(512), dim3(256), 0, stream,
                           qb, kb, vtb, part, lsum_buf, counter, cntp, slist);
        hipLaunchKernelGGL(combine_kernel, dim3(256), dim3(256), 0, stream,
                           part, lsum_buf, ob, cntp, slist);
    } else {
        hipLaunchKernelGGL(attn_kernel, dim3(256), dim3(256), 0, stream, qb, kb, vtb, ob);
    }
    hipLaunchKernelGGL(gemm_kernel, dim3(128, 4), dim3(256), 0, stream, ob, wob, bo, x, d_out, flag);
}